// Round 8
// baseline (943.040 us; speedup 1.0000x reference)
//
#include <hip/hip_runtime.h>

// GCN forward, round 8: binned-COO + LDS-accumulator formulation.
// Edges are counting-sorted into 400 bins of 250 dst-nodes (packed codes);
// aggregation happens per-bin in LDS (ds_add_f32) — no CSR, no per-edge
// global atomics, no placement scatter.
//
//   dis[n] = rsqrt(deg_in[n] + 1)
//   layer1: aggx[n] = sx[n] + sum_{s->n} sx[s],  sx = (x*dis) fp16 [8-padded]
//           h1[n]   = lrelu(dis[n]*(aggx[n] @ W1) + b1)   [64] (LDS only)
//   layer2: t2[n]   = dis[n]*(h1[n] @ W2)  fp16            [32]
//           h2[n]   = lrelu(dis[n]*(t2[n] + sum t2[s]) + b2)
//   pool:   gsum[batch[n]] += h2[n];  out = (gsum/cnt) @ Wlin + blin

#define N_NODES 100000
#define N_EDGES 3200000
#define N_GRAPHS 1024
#define IN_F 6
#define H1 64
#define H2 32
#define SLOPE 0.01f

#define NBK 8                // pass-A dst buckets
#define BROW 12500           // nodes per bucket
#define BCAP 408000          // per-bucket edge capacity
#define BIN_SEG 4096         // edges per k_bin block
#define E4 (N_EDGES / 4)

#define NBIN 400             // total bins (50 per bucket)
#define BIN_N 250            // nodes per bin
#define CAP2 8704            // per-bin edge capacity (8000 avg + ~8 sigma)

typedef _Float16 f16;

static __device__ __forceinline__ float lrelu(float v) {
    return v > 0.0f ? v : SLOPE * v;
}

// ---- pass A: bin edges by dst bucket, code = src<<14 | dst_local ----
__global__ void k_bin(const int* __restrict__ src, const int* __restrict__ dst,
                      int* __restrict__ bcur, unsigned* __restrict__ benc) {
    __shared__ int cnt[NBK], base[NBK], lcur[NBK];
    int tid = threadIdx.x;
    if (tid < NBK) cnt[tid] = 0;
    __syncthreads();
    const int4* s4 = (const int4*)src;
    const int4* d4 = (const int4*)dst;
    int i0 = blockIdx.x * (BIN_SEG / 4);
#pragma unroll
    for (int k = 0; k < 4; ++k) {
        int i4 = i0 + tid + k * 256;
        if (i4 < E4) {
            int4 dv = d4[i4];
            atomicAdd(&cnt[dv.x / BROW], 1);
            atomicAdd(&cnt[dv.y / BROW], 1);
            atomicAdd(&cnt[dv.z / BROW], 1);
            atomicAdd(&cnt[dv.w / BROW], 1);
        }
    }
    __syncthreads();
    if (tid < NBK) { base[tid] = atomicAdd(&bcur[tid], cnt[tid]); lcur[tid] = 0; }
    __syncthreads();
#pragma unroll
    for (int k = 0; k < 4; ++k) {
        int i4 = i0 + tid + k * 256;
        if (i4 < E4) {
            int4 dv = d4[i4];
            int4 sv = s4[i4];
            int b, p;
            b = dv.x / BROW; p = atomicAdd(&lcur[b], 1);
            benc[(long long)b * BCAP + base[b] + p] = ((unsigned)sv.x << 14) | (unsigned)(dv.x - b * BROW);
            b = dv.y / BROW; p = atomicAdd(&lcur[b], 1);
            benc[(long long)b * BCAP + base[b] + p] = ((unsigned)sv.y << 14) | (unsigned)(dv.y - b * BROW);
            b = dv.z / BROW; p = atomicAdd(&lcur[b], 1);
            benc[(long long)b * BCAP + base[b] + p] = ((unsigned)sv.z << 14) | (unsigned)(dv.z - b * BROW);
            b = dv.w / BROW; p = atomicAdd(&lcur[b], 1);
            benc[(long long)b * BCAP + base[b] + p] = ((unsigned)sv.w << 14) | (unsigned)(dv.w - b * BROW);
        }
    }
}

// ---- pass B: bucket -> 50 sub-bins of 250 nodes, code2 = src<<8 | r ----
__global__ void k_binB(const unsigned* __restrict__ benc, const int* __restrict__ bcur,
                       int* __restrict__ bcur2, unsigned* __restrict__ benc2) {
    __shared__ int hist[50], base[50], lcur[50];
    int bk = blockIdx.x & (NBK - 1);
    int grp = blockIdx.x >> 3;           // 0..127
    const int NG = 128;
    int cnt = bcur[bk];
    int chunk = (cnt + NG - 1) / NG;
    int lo = grp * chunk;
    int hi = lo + chunk; if (hi > cnt) hi = cnt;
    const unsigned* p = benc + (long long)bk * BCAP;
    int tid = threadIdx.x;
    if (tid < 50) hist[tid] = 0;
    __syncthreads();
    for (int i = lo + tid; i < hi; i += 256)
        atomicAdd(&hist[(int)(p[i] & 0x3FFFu) / BIN_N], 1);
    __syncthreads();
    if (tid < 50) {
        base[tid] = atomicAdd(&bcur2[bk * 50 + tid], hist[tid]);
        lcur[tid] = 0;
    }
    __syncthreads();
    for (int i = lo + tid; i < hi; i += 256) {
        unsigned c = p[i];
        int dl = (int)(c & 0x3FFFu);
        int q = dl / BIN_N;
        int r = dl - q * BIN_N;
        int pos = atomicAdd(&lcur[q], 1);
        benc2[(long long)(bk * 50 + q) * CAP2 + base[q] + pos] = ((c >> 14) << 8) | (unsigned)r;
    }
}

// ---- per-bin degree histogram -> dis, sx (fp16, stride 8) ----
__global__ void k_degsx(const unsigned* __restrict__ benc2, const int* __restrict__ bcur2,
                        const float* __restrict__ x, float* __restrict__ dis,
                        f16* __restrict__ sx) {
    __shared__ int hist[BIN_N];
    int bin = blockIdx.x;
    int tid = threadIdx.x;
    if (tid < BIN_N) hist[tid] = 0;
    __syncthreads();
    int cnt = bcur2[bin];
    const unsigned* p = benc2 + (long long)bin * CAP2;
    for (int i = tid; i < cnt; i += 256)
        atomicAdd(&hist[p[i] & 0xFFu], 1);
    __syncthreads();
    if (tid < BIN_N) {
        int n = bin * BIN_N + tid;
        float dn = rsqrtf((float)(hist[tid] + 1));
        dis[n] = dn;
#pragma unroll
        for (int j = 0; j < IN_F; ++j)
            sx[n * 8 + j] = (f16)(x[n * IN_F + j] * dn);
        sx[n * 8 + 6] = (f16)0.0f;
        sx[n * 8 + 7] = (f16)0.0f;
    }
}

// ---- layer-1 aggregation: LDS acc[250][8], 8 lanes/edge, unroll x8 ----
__global__ void k_agg1(const unsigned* __restrict__ benc2, const int* __restrict__ bcur2,
                       const f16* __restrict__ sx, float* __restrict__ aggx) {
    __shared__ float acc[BIN_N * 8];
    int bin = blockIdx.x;
    int tid = threadIdx.x;
    for (int i = tid; i < BIN_N * 8; i += 256) acc[i] = 0.0f;
    __syncthreads();
    int cnt = bcur2[bin];
    const unsigned* p = benc2 + (long long)bin * CAP2;
    int slot = tid >> 3;   // 0..31
    int f = tid & 7;
    for (int j0 = slot * 8; j0 < cnt; j0 += 256) {
        int m = cnt - j0; if (m > 8) m = 8;
        unsigned c0 = p[j0];
        unsigned c1 = (1 < m) ? p[j0 + 1] : 0u;
        unsigned c2 = (2 < m) ? p[j0 + 2] : 0u;
        unsigned c3 = (3 < m) ? p[j0 + 3] : 0u;
        unsigned c4 = (4 < m) ? p[j0 + 4] : 0u;
        unsigned c5 = (5 < m) ? p[j0 + 5] : 0u;
        unsigned c6 = (6 < m) ? p[j0 + 6] : 0u;
        unsigned c7 = (7 < m) ? p[j0 + 7] : 0u;
        float v0 = (float)sx[(c0 >> 8) * 8 + f];
        float v1 = (1 < m) ? (float)sx[(c1 >> 8) * 8 + f] : 0.0f;
        float v2 = (2 < m) ? (float)sx[(c2 >> 8) * 8 + f] : 0.0f;
        float v3 = (3 < m) ? (float)sx[(c3 >> 8) * 8 + f] : 0.0f;
        float v4 = (4 < m) ? (float)sx[(c4 >> 8) * 8 + f] : 0.0f;
        float v5 = (5 < m) ? (float)sx[(c5 >> 8) * 8 + f] : 0.0f;
        float v6 = (6 < m) ? (float)sx[(c6 >> 8) * 8 + f] : 0.0f;
        float v7 = (7 < m) ? (float)sx[(c7 >> 8) * 8 + f] : 0.0f;
        atomicAdd(&acc[(c0 & 0xFFu) * 8 + f], v0);
        if (1 < m) atomicAdd(&acc[(c1 & 0xFFu) * 8 + f], v1);
        if (2 < m) atomicAdd(&acc[(c2 & 0xFFu) * 8 + f], v2);
        if (3 < m) atomicAdd(&acc[(c3 & 0xFFu) * 8 + f], v3);
        if (4 < m) atomicAdd(&acc[(c4 & 0xFFu) * 8 + f], v4);
        if (5 < m) atomicAdd(&acc[(c5 & 0xFFu) * 8 + f], v5);
        if (6 < m) atomicAdd(&acc[(c6 & 0xFFu) * 8 + f], v6);
        if (7 < m) atomicAdd(&acc[(c7 & 0xFFu) * 8 + f], v7);
    }
    __syncthreads();
    int n0 = bin * BIN_N;
    for (int i = tid; i < BIN_N * 8; i += 256) {
        int n = i >> 3, ff = i & 7;
        aggx[(n0 + n) * 8 + ff] = acc[i] + (float)sx[(n0 + n) * 8 + ff];
    }
}

// fused: h1 = lrelu(dis*(aggx@W1)+b1) (LDS only), t2 = dis*(h1@W2) fp16
__global__ void k_h1t2(const float* __restrict__ aggx, const float* __restrict__ W1,
                       const float* __restrict__ b1, const float* __restrict__ W2,
                       const float* __restrict__ dis, f16* __restrict__ t2) {
    __shared__ float sW1[IN_F * H1];
    __shared__ float sb1[H1];
    __shared__ float sW2[H1 * H2];
    __shared__ float sh1[8][H1];
    int tid = threadIdx.x;
    for (int i = tid; i < IN_F * H1; i += 256) sW1[i] = W1[i];
    if (tid < H1) sb1[tid] = b1[tid];
    for (int i = tid; i < H1 * H2; i += 256) sW2[i] = W2[i];
    int loc = tid >> 5;
    int lane = tid & 31;
    int n = blockIdx.x * 8 + loc;
    bool ok = n < N_NODES;
    float a[IN_F];
    float dn = 0.0f;
    if (ok) {
        dn = dis[n];
#pragma unroll
        for (int j = 0; j < IN_F; ++j) a[j] = aggx[n * 8 + j];
    }
    __syncthreads();
    if (ok) {
#pragma unroll
        for (int kk = 0; kk < 2; ++kk) {
            int k = lane + kk * 32;
            float s = 0.0f;
#pragma unroll
            for (int j = 0; j < IN_F; ++j) s += a[j] * sW1[j * H1 + k];
            sh1[loc][k] = lrelu(s * dn + sb1[k]);
        }
    }
    __syncthreads();
    if (ok) {
        float s = 0.0f;
#pragma unroll
        for (int k = 0; k < H1; ++k) s += sh1[loc][k] * sW2[k * H2 + lane];
        t2[n * H2 + lane] = (f16)(s * dn);
    }
}

// ---- layer-2 aggregation + lrelu + per-graph pooling, all in LDS ----
__global__ void k_agg2(const unsigned* __restrict__ benc2, const int* __restrict__ bcur2,
                       const f16* __restrict__ t2, const float* __restrict__ dis,
                       const float* __restrict__ b2, const int* __restrict__ batch,
                       float* __restrict__ gsum, float* __restrict__ gcnt) {
    __shared__ float acc[BIN_N * H2];    // 32 KB
    __shared__ int sbatch[BIN_N];
    int bin = blockIdx.x;
    int tid = threadIdx.x;
    for (int i = tid; i < BIN_N * H2; i += 256) acc[i] = 0.0f;
    __syncthreads();
    int cnt = bcur2[bin];
    const unsigned* p = benc2 + (long long)bin * CAP2;
    int half = tid >> 5;   // 0..7
    int f = tid & 31;
    for (int j0 = half * 8; j0 < cnt; j0 += 64) {
        int m = cnt - j0; if (m > 8) m = 8;
        unsigned c0 = p[j0];
        unsigned c1 = (1 < m) ? p[j0 + 1] : 0u;
        unsigned c2 = (2 < m) ? p[j0 + 2] : 0u;
        unsigned c3 = (3 < m) ? p[j0 + 3] : 0u;
        unsigned c4 = (4 < m) ? p[j0 + 4] : 0u;
        unsigned c5 = (5 < m) ? p[j0 + 5] : 0u;
        unsigned c6 = (6 < m) ? p[j0 + 6] : 0u;
        unsigned c7 = (7 < m) ? p[j0 + 7] : 0u;
        float v0 = (float)t2[(c0 >> 8) * H2 + f];
        float v1 = (1 < m) ? (float)t2[(c1 >> 8) * H2 + f] : 0.0f;
        float v2 = (2 < m) ? (float)t2[(c2 >> 8) * H2 + f] : 0.0f;
        float v3 = (3 < m) ? (float)t2[(c3 >> 8) * H2 + f] : 0.0f;
        float v4 = (4 < m) ? (float)t2[(c4 >> 8) * H2 + f] : 0.0f;
        float v5 = (5 < m) ? (float)t2[(c5 >> 8) * H2 + f] : 0.0f;
        float v6 = (6 < m) ? (float)t2[(c6 >> 8) * H2 + f] : 0.0f;
        float v7 = (7 < m) ? (float)t2[(c7 >> 8) * H2 + f] : 0.0f;
        atomicAdd(&acc[(c0 & 0xFFu) * H2 + f], v0);
        if (1 < m) atomicAdd(&acc[(c1 & 0xFFu) * H2 + f], v1);
        if (2 < m) atomicAdd(&acc[(c2 & 0xFFu) * H2 + f], v2);
        if (3 < m) atomicAdd(&acc[(c3 & 0xFFu) * H2 + f], v3);
        if (4 < m) atomicAdd(&acc[(c4 & 0xFFu) * H2 + f], v4);
        if (5 < m) atomicAdd(&acc[(c5 & 0xFFu) * H2 + f], v5);
        if (6 < m) atomicAdd(&acc[(c6 & 0xFFu) * H2 + f], v6);
        if (7 < m) atomicAdd(&acc[(c7 & 0xFFu) * H2 + f], v7);
    }
    int n0 = bin * BIN_N;
    for (int i = tid; i < BIN_N; i += 256) sbatch[i] = batch[n0 + i];
    __syncthreads();
    // epilogue: self term + scale + lrelu, in place
    for (int i = tid; i < BIN_N * H2; i += 256) {
        int n = i >> 5, ff = i & 31;
        float s = acc[i] + (float)t2[(n0 + n) * H2 + ff];
        float v = s * dis[n0 + n] + b2[ff];
        acc[i] = v > 0.0f ? v : SLOPE * v;
    }
    __syncthreads();
    // per-graph pooling: bin spans ~3 consecutive graph ids
    int gmin = sbatch[0], gmax = sbatch[BIN_N - 1];
    for (int g = gmin + half; g <= gmax; g += 8) {
        float s = 0.0f; int c = 0;
        for (int n = 0; n < BIN_N; ++n)
            if (sbatch[n] == g) { s += acc[n * H2 + f]; ++c; }
        if (c > 0) {
            atomicAdd(&gsum[g * H2 + f], s);
            if (f == 0) atomicAdd(&gcnt[g], (float)c);
        }
    }
}

__global__ void k_final(const float* __restrict__ gsum, const float* __restrict__ gcnt,
                        const float* __restrict__ Wlin, const float* __restrict__ blin,
                        float* __restrict__ out) {
    int idx = blockIdx.x * blockDim.x + threadIdx.x;
    if (idx >= N_GRAPHS * 2) return;
    int g = idx >> 1;
    int t = idx & 1;
    float inv = 1.0f / fmaxf(gcnt[g], 1.0f);
    float s = blin[t];
#pragma unroll
    for (int ff = 0; ff < H2; ++ff)
        s += gsum[g * H2 + ff] * inv * Wlin[ff * 2 + t];
    out[idx] = s;
}

static inline int cdiv(long long a, int b) { return (int)((a + b - 1) / b); }

extern "C" void kernel_launch(void* const* d_in, const int* in_sizes, int n_in,
                              void* d_out, int out_size, void* d_ws, size_t ws_size,
                              hipStream_t stream) {
    const float* x    = (const float*)d_in[0];
    const int*   ei   = (const int*)d_in[1];
    const int*   batch= (const int*)d_in[2];
    const float* W1   = (const float*)d_in[3];
    const float* b1   = (const float*)d_in[4];
    const float* W2   = (const float*)d_in[5];
    const float* b2   = (const float*)d_in[6];
    const float* Wlin = (const float*)d_in[7];
    const float* blin = (const float*)d_in[8];
    float* out = (float*)d_out;

    const int* src = ei;
    const int* dst = ei + N_EDGES;

    // ---- workspace layout ----
    f16*   t2   = (f16*)d_ws;                           // 32N fp16
    f16*   sx   = t2 + 32LL * N_NODES;                  // 8N fp16
    float* dis  = (float*)(sx + 8LL * N_NODES);         // N f32
    float* aggx = dis + N_NODES;                        // 8N f32
    float* gsum = aggx + 8LL * N_NODES;                 // 32G
    float* gcnt = gsum + (long long)N_GRAPHS * H2;      // G
    size_t ioff = ((size_t)(gcnt + N_GRAPHS) + 15) & ~(size_t)15;
    int*  bcur    = (int*)ioff;                         // NBK
    int*  bcur2   = bcur + NBK;                         // NBIN
    unsigned* benc  = (unsigned*)(bcur2 + NBIN + 8);    // NBK*BCAP
    unsigned* benc2 = benc + (long long)NBK * BCAP;     // NBIN*CAP2

    const int B = 256;

    hipMemsetAsync(gsum, 0, sizeof(float) * (N_GRAPHS * H2 + N_GRAPHS), stream);
    hipMemsetAsync(bcur, 0, sizeof(int) * (NBK + NBIN + 8), stream);

    k_bin<<<cdiv(N_EDGES, BIN_SEG), B, 0, stream>>>(src, dst, bcur, benc);
    k_binB<<<1024, B, 0, stream>>>(benc, bcur, bcur2, benc2);
    k_degsx<<<NBIN, B, 0, stream>>>(benc2, bcur2, x, dis, sx);
    k_agg1<<<NBIN, B, 0, stream>>>(benc2, bcur2, sx, aggx);
    k_h1t2<<<cdiv(N_NODES, 8), B, 0, stream>>>(aggx, W1, b1, W2, dis, t2);
    k_agg2<<<NBIN, B, 0, stream>>>(benc2, bcur2, t2, dis, b2, batch, gsum, gcnt);
    k_final<<<cdiv(N_GRAPHS * 2, B), B, 0, stream>>>(gsum, gcnt, Wlin, blin, out);
}

// Round 9
// 179.632 us; speedup vs baseline: 5.2498x; 5.2498x over previous
//
#include <hip/hip_runtime.h>

// GCN forward, round 9: 2-level counting-bin build + per-bin LDS counting
// sort into windowed CSR + massively-parallel CSR gathers (fp16 tables).
//
//   dis[n] = rsqrt(deg_in[n] + 1)
//   layer1: aggx[n] = sx[n] + sum_{s->n} sx[s],  sx = (x*dis) fp16 [8-padded]
//           h1[n]   = lrelu(dis[n]*(aggx[n] @ W1) + b1)   [64] (LDS only)
//   layer2: t2[n]   = dis[n]*(h1[n] @ W2)  fp16            [32]
//           h2[n]   = lrelu(dis[n]*(t2[n] + sum t2[s]) + b2)
//   pool:   gsum[batch[n]] += h2[n];  out = (gsum/cnt) @ Wlin + blin

#define N_NODES 100000
#define N_EDGES 3200000
#define N_GRAPHS 1024
#define IN_F 6
#define H1 64
#define H2 32
#define SLOPE 0.01f

#define NBK 8                // pass-A dst buckets
#define BROW 12500           // nodes per bucket
#define BCAP 408000          // per-bucket edge capacity
#define BIN_SEG 4096         // edges per k_bin block
#define E4 (N_EDGES / 4)

#define NBIN 400             // total bins (50 per bucket)
#define BIN_N 250            // nodes per bin
#define CAP2 8704            // per-bin edge capacity (8000 avg + ~8 sigma)
#define CAP2R 10752          // per-bin padded CSR window (>= CAP2 + 250*7, /8)

typedef _Float16 f16;

static __device__ __forceinline__ float lrelu(float v) {
    return v > 0.0f ? v : SLOPE * v;
}

// ---- pass A: bin edges by dst bucket, code = src<<14 | dst_local ----
__global__ void k_bin(const int* __restrict__ src, const int* __restrict__ dst,
                      int* __restrict__ bcur, unsigned* __restrict__ benc) {
    __shared__ int cnt[NBK], base[NBK], lcur[NBK];
    int tid = threadIdx.x;
    if (tid < NBK) cnt[tid] = 0;
    __syncthreads();
    const int4* s4 = (const int4*)src;
    const int4* d4 = (const int4*)dst;
    int i0 = blockIdx.x * (BIN_SEG / 4);
#pragma unroll
    for (int k = 0; k < 4; ++k) {
        int i4 = i0 + tid + k * 256;
        if (i4 < E4) {
            int4 dv = d4[i4];
            atomicAdd(&cnt[dv.x / BROW], 1);
            atomicAdd(&cnt[dv.y / BROW], 1);
            atomicAdd(&cnt[dv.z / BROW], 1);
            atomicAdd(&cnt[dv.w / BROW], 1);
        }
    }
    __syncthreads();
    if (tid < NBK) { base[tid] = atomicAdd(&bcur[tid], cnt[tid]); lcur[tid] = 0; }
    __syncthreads();
#pragma unroll
    for (int k = 0; k < 4; ++k) {
        int i4 = i0 + tid + k * 256;
        if (i4 < E4) {
            int4 dv = d4[i4];
            int4 sv = s4[i4];
            int b, p;
            b = dv.x / BROW; p = atomicAdd(&lcur[b], 1);
            benc[(long long)b * BCAP + base[b] + p] = ((unsigned)sv.x << 14) | (unsigned)(dv.x - b * BROW);
            b = dv.y / BROW; p = atomicAdd(&lcur[b], 1);
            benc[(long long)b * BCAP + base[b] + p] = ((unsigned)sv.y << 14) | (unsigned)(dv.y - b * BROW);
            b = dv.z / BROW; p = atomicAdd(&lcur[b], 1);
            benc[(long long)b * BCAP + base[b] + p] = ((unsigned)sv.z << 14) | (unsigned)(dv.z - b * BROW);
            b = dv.w / BROW; p = atomicAdd(&lcur[b], 1);
            benc[(long long)b * BCAP + base[b] + p] = ((unsigned)sv.w << 14) | (unsigned)(dv.w - b * BROW);
        }
    }
}

// ---- pass B: bucket -> 50 sub-bins of 250 nodes, code2 = src<<8 | r ----
__global__ void k_binB(const unsigned* __restrict__ benc, const int* __restrict__ bcur,
                       int* __restrict__ bcur2, unsigned* __restrict__ benc2) {
    __shared__ int hist[50], base[50], lcur[50];
    int bk = blockIdx.x & (NBK - 1);
    int grp = blockIdx.x >> 3;           // 0..127
    const int NG = 128;
    int cnt = bcur[bk];
    int chunk = (cnt + NG - 1) / NG;
    int lo = grp * chunk;
    int hi = lo + chunk; if (hi > cnt) hi = cnt;
    const unsigned* p = benc + (long long)bk * BCAP;
    int tid = threadIdx.x;
    if (tid < 50) hist[tid] = 0;
    __syncthreads();
    for (int i = lo + tid; i < hi; i += 256)
        atomicAdd(&hist[(int)(p[i] & 0x3FFFu) / BIN_N], 1);
    __syncthreads();
    if (tid < 50) {
        base[tid] = atomicAdd(&bcur2[bk * 50 + tid], hist[tid]);
        lcur[tid] = 0;
    }
    __syncthreads();
    for (int i = lo + tid; i < hi; i += 256) {
        unsigned c = p[i];
        int dl = (int)(c & 0x3FFFu);
        int q = dl / BIN_N;
        int r = dl - q * BIN_N;
        int pos = atomicAdd(&lcur[q], 1);
        benc2[(long long)(bk * 50 + q) * CAP2 + base[q] + pos] = ((c >> 14) << 8) | (unsigned)r;
    }
}

// ---- per-bin LDS counting sort -> windowed CSR + deg/dis/sx ----
// One block per bin. No global atomics; all cursors in LDS; CSR writes land
// in the bin's private 42KB window (lines fill before eviction).
__global__ void k_sort(const unsigned* __restrict__ benc2, const int* __restrict__ bcur2,
                       const float* __restrict__ x,
                       int* __restrict__ csr, int* __restrict__ obeg, int* __restrict__ oend,
                       float* __restrict__ dis, f16* __restrict__ sx) {
    __shared__ int hist[256];
    __shared__ int scn[256];
    __shared__ int lcur[256];
    int bin = blockIdx.x;
    int tid = threadIdx.x;
    hist[tid] = 0;
    __syncthreads();
    int cnt = bcur2[bin];
    const unsigned* p = benc2 + (long long)bin * CAP2;
    for (int i = tid; i < cnt; i += 256)
        atomicAdd(&hist[p[i] & 0xFFu], 1);
    __syncthreads();
    int deg = hist[tid];
    int pad = (deg + 7) & ~7;
    scn[tid] = pad;
    __syncthreads();
    for (int off = 1; off < 256; off <<= 1) {
        int v = 0;
        if (tid >= off) v = scn[tid - off];
        __syncthreads();
        if (tid >= off) scn[tid] += v;
        __syncthreads();
    }
    int excl = scn[tid] - pad;               // exclusive scan of padded degs
    int gbase = bin * CAP2R;
    lcur[tid] = gbase + excl;
    if (tid < BIN_N) {
        int n = bin * BIN_N + tid;
        obeg[n] = gbase + excl;
        oend[n] = gbase + excl + pad;
        float dn = rsqrtf((float)(deg + 1));
        dis[n] = dn;
#pragma unroll
        for (int j = 0; j < IN_F; ++j)
            sx[n * 8 + j] = (f16)(x[n * IN_F + j] * dn);
        sx[n * 8 + 6] = (f16)0.0f;
        sx[n * 8 + 7] = (f16)0.0f;
    }
    __syncthreads();
    for (int i = tid; i < cnt; i += 256) {
        unsigned c = p[i];
        int pos = atomicAdd(&lcur[c & 0xFFu], 1);
        csr[pos] = (int)(c >> 8);
    }
    __syncthreads();
    if (tid < BIN_N) {
        int end = gbase + excl + pad;
        for (int j = lcur[tid]; j < end; ++j) csr[j] = N_NODES;   // zero-row pad
    }
}

// aggx[n,f] = sx[n,f] + sum over incoming neighbors; 8 lanes/node, unroll x8
__global__ void k_gather1(const f16* __restrict__ sx, const int* __restrict__ obeg,
                          const int* __restrict__ oend, const int* __restrict__ csr,
                          float* __restrict__ aggx) {
    int idx = blockIdx.x * blockDim.x + threadIdx.x;
    int n = idx >> 3;
    int f = idx & 7;
    float acc = (float)sx[(n << 3) + f];
    int b = obeg[n], e = oend[n];
    for (int j = b; j < e; j += 8) {
        const int4* p = (const int4*)(csr + j);
        int4 ia = p[0], ib = p[1];
        float v0 = (float)sx[(ia.x << 3) + f], v1 = (float)sx[(ia.y << 3) + f];
        float v2 = (float)sx[(ia.z << 3) + f], v3 = (float)sx[(ia.w << 3) + f];
        float v4 = (float)sx[(ib.x << 3) + f], v5 = (float)sx[(ib.y << 3) + f];
        float v6 = (float)sx[(ib.z << 3) + f], v7 = (float)sx[(ib.w << 3) + f];
        acc += ((v0 + v1) + (v2 + v3)) + ((v4 + v5) + (v6 + v7));
    }
    aggx[(n << 3) + f] = acc;
}

// fused: h1 = lrelu(dis*(aggx@W1)+b1) (LDS only), t2 = dis*(h1@W2) fp16
__global__ void k_h1t2(const float* __restrict__ aggx, const float* __restrict__ W1,
                       const float* __restrict__ b1, const float* __restrict__ W2,
                       const float* __restrict__ dis, f16* __restrict__ t2) {
    __shared__ float sW1[IN_F * H1];
    __shared__ float sb1[H1];
    __shared__ float sW2[H1 * H2];
    __shared__ float sh1[8][H1];
    int tid = threadIdx.x;
    for (int i = tid; i < IN_F * H1; i += 256) sW1[i] = W1[i];
    if (tid < H1) sb1[tid] = b1[tid];
    for (int i = tid; i < H1 * H2; i += 256) sW2[i] = W2[i];
    int loc = tid >> 5;
    int lane = tid & 31;
    int n = blockIdx.x * 8 + loc;
    float a[IN_F];
    float dn = dis[n];
#pragma unroll
    for (int j = 0; j < IN_F; ++j) a[j] = aggx[n * 8 + j];
    __syncthreads();
#pragma unroll
    for (int kk = 0; kk < 2; ++kk) {
        int k = lane + kk * 32;
        float s = 0.0f;
#pragma unroll
        for (int j = 0; j < IN_F; ++j) s += a[j] * sW1[j * H1 + k];
        sh1[loc][k] = lrelu(s * dn + sb1[k]);
    }
    __syncthreads();
    float s = 0.0f;
#pragma unroll
    for (int k = 0; k < H1; ++k) s += sh1[loc][k] * sW2[k * H2 + lane];
    t2[n * H2 + lane] = (f16)(s * dn);
}

// agg2 gather (unroll x16) + lrelu + LDS-deduped mean-pool accumulation
__global__ void k_gather2(const f16* __restrict__ t2, const int* __restrict__ obeg,
                          const int* __restrict__ oend, const int* __restrict__ csr,
                          const float* __restrict__ dis, const float* __restrict__ b2,
                          const int* __restrict__ batch,
                          float* __restrict__ gsum, float* __restrict__ gcnt) {
    __shared__ float sv[8][H2];
    __shared__ int sg[8];
    int idx = blockIdx.x * blockDim.x + threadIdx.x;
    int n = idx >> 5;
    int f = idx & 31;
    float acc = (float)t2[(n << 5) + f];
    int b = obeg[n], e = oend[n];
    int j = b;
    for (; j + 16 <= e; j += 16) {
        const int4* p = (const int4*)(csr + j);
        int4 ia = p[0], ib = p[1], ic = p[2], id = p[3];
        float v0 = (float)t2[(ia.x << 5) + f], v1 = (float)t2[(ia.y << 5) + f];
        float v2 = (float)t2[(ia.z << 5) + f], v3 = (float)t2[(ia.w << 5) + f];
        float v4 = (float)t2[(ib.x << 5) + f], v5 = (float)t2[(ib.y << 5) + f];
        float v6 = (float)t2[(ib.z << 5) + f], v7 = (float)t2[(ib.w << 5) + f];
        float v8 = (float)t2[(ic.x << 5) + f], v9 = (float)t2[(ic.y << 5) + f];
        float va = (float)t2[(ic.z << 5) + f], vb = (float)t2[(ic.w << 5) + f];
        float vc = (float)t2[(id.x << 5) + f], vd = (float)t2[(id.y << 5) + f];
        float ve = (float)t2[(id.z << 5) + f], vf = (float)t2[(id.w << 5) + f];
        acc += (((v0 + v1) + (v2 + v3)) + ((v4 + v5) + (v6 + v7)))
             + (((v8 + v9) + (va + vb)) + ((vc + vd) + (ve + vf)));
    }
    if (j < e) {
        const int4* p = (const int4*)(csr + j);
        int4 ia = p[0], ib = p[1];
        float v0 = (float)t2[(ia.x << 5) + f], v1 = (float)t2[(ia.y << 5) + f];
        float v2 = (float)t2[(ia.z << 5) + f], v3 = (float)t2[(ia.w << 5) + f];
        float v4 = (float)t2[(ib.x << 5) + f], v5 = (float)t2[(ib.y << 5) + f];
        float v6 = (float)t2[(ib.z << 5) + f], v7 = (float)t2[(ib.w << 5) + f];
        acc += ((v0 + v1) + (v2 + v3)) + ((v4 + v5) + (v6 + v7));
    }
    float v = lrelu(acc * dis[n] + b2[f]);
    int g = batch[n];
    int loc = threadIdx.x >> 5;
    sv[loc][f] = v;
    if (f == 0) sg[loc] = g;
    __syncthreads();
    bool leader = true;
    for (int l = 0; l < loc; ++l) leader &= (sg[l] != g);
    if (leader) {
        float s = v;
        float c = 1.0f;
        for (int l = loc + 1; l < 8; ++l)
            if (sg[l] == g) { s += sv[l][f]; c += 1.0f; }
        atomicAdd(&gsum[g * H2 + f], s);
        if (f == 0) atomicAdd(&gcnt[g], c);
    }
}

__global__ void k_final(const float* __restrict__ gsum, const float* __restrict__ gcnt,
                        const float* __restrict__ Wlin, const float* __restrict__ blin,
                        float* __restrict__ out) {
    int idx = blockIdx.x * blockDim.x + threadIdx.x;
    if (idx >= N_GRAPHS * 2) return;
    int g = idx >> 1;
    int t = idx & 1;
    float inv = 1.0f / fmaxf(gcnt[g], 1.0f);
    float s = blin[t];
#pragma unroll
    for (int ff = 0; ff < H2; ++ff)
        s += gsum[g * H2 + ff] * inv * Wlin[ff * 2 + t];
    out[idx] = s;
}

static inline int cdiv(long long a, int b) { return (int)((a + b - 1) / b); }

extern "C" void kernel_launch(void* const* d_in, const int* in_sizes, int n_in,
                              void* d_out, int out_size, void* d_ws, size_t ws_size,
                              hipStream_t stream) {
    const float* x    = (const float*)d_in[0];
    const int*   ei   = (const int*)d_in[1];
    const int*   batch= (const int*)d_in[2];
    const float* W1   = (const float*)d_in[3];
    const float* b1   = (const float*)d_in[4];
    const float* W2   = (const float*)d_in[5];
    const float* b2   = (const float*)d_in[6];
    const float* Wlin = (const float*)d_in[7];
    const float* blin = (const float*)d_in[8];
    float* out = (float*)d_out;

    const int* src = ei;
    const int* dst = ei + N_EDGES;

    // ---- workspace layout ----
    f16*   t2   = (f16*)d_ws;                           // 32*(N+1) fp16
    f16*   sx   = t2 + 32LL * (N_NODES + 1);            // 8*(N+1) fp16
    float* dis  = (float*)(sx + 8LL * (N_NODES + 1));   // N f32
    float* aggx = dis + N_NODES;                        // 8N f32
    float* gsum = aggx + 8LL * N_NODES;                 // 32G
    float* gcnt = gsum + (long long)N_GRAPHS * H2;      // G
    size_t ioff = ((size_t)(gcnt + N_GRAPHS) + 15) & ~(size_t)15;
    int*  bcur    = (int*)ioff;                         // NBK
    int*  bcur2   = bcur + NBK;                         // NBIN (+pad to 16B)
    int*  obeg    = bcur2 + NBIN + 8;                   // N
    int*  oend    = obeg + N_NODES;                     // N
    unsigned* benc  = (unsigned*)(oend + N_NODES);      // NBK*BCAP
    unsigned* benc2 = benc + (long long)NBK * BCAP;     // NBIN*CAP2
    int*  csr      = (int*)(benc2 + (long long)NBIN * CAP2);  // NBIN*CAP2R

    const int B = 256;

    hipMemsetAsync(gsum, 0, sizeof(float) * (N_GRAPHS * H2 + N_GRAPHS), stream);
    hipMemsetAsync(bcur, 0, sizeof(int) * (NBK + NBIN + 8), stream);
    hipMemsetAsync(t2 + 32LL * N_NODES, 0, 32 * sizeof(f16), stream);  // zero row
    hipMemsetAsync(sx + 8LL * N_NODES, 0, 8 * sizeof(f16), stream);    // zero row

    k_bin<<<cdiv(N_EDGES, BIN_SEG), B, 0, stream>>>(src, dst, bcur, benc);
    k_binB<<<1024, B, 0, stream>>>(benc, bcur, bcur2, benc2);
    k_sort<<<NBIN, B, 0, stream>>>(benc2, bcur2, x, csr, obeg, oend, dis, sx);

    k_gather1<<<cdiv((long long)N_NODES * 8, B), B, 0, stream>>>(sx, obeg, oend, csr, aggx);
    k_h1t2<<<cdiv(N_NODES, 8), B, 0, stream>>>(aggx, W1, b1, W2, dis, t2);
    k_gather2<<<cdiv((long long)N_NODES * H2, B), B, 0, stream>>>(t2, obeg, oend, csr, dis,
                                                                  b2, batch, gsum, gcnt);
    k_final<<<cdiv(N_GRAPHS * 2, B), B, 0, stream>>>(gsum, gcnt, Wlin, blin, out);
}

// Round 11
// 176.715 us; speedup vs baseline: 5.3365x; 1.0165x over previous
//
#include <hip/hip_runtime.h>

// GCN forward, round 11: same as round 10 but with clang ext_vector types
// for nontemporal loads (HIP int4 is a class; the builtin rejects it).
//
//   dis[n] = rsqrt(deg_in[n] + 1)
//   layer1: aggx[n] = sx[n] + sum_{s->n} sx[s],  sx = (x*dis) fp16 [8-padded]
//           h1[n]   = lrelu(dis[n]*(aggx[n] @ W1) + b1)   [64] (LDS only)
//   layer2: t2[n]   = dis[n]*(h1[n] @ W2)  fp16            [32]
//           h2[n]   = lrelu(dis[n]*(t2[n] + sum t2[s]) + b2)
//   pool:   gsum[batch[n]] += h2[n];  out = (gsum/cnt) @ Wlin + blin

#define N_NODES 100000
#define N_EDGES 3200000
#define N_GRAPHS 1024
#define IN_F 6
#define H1 64
#define H2 32
#define SLOPE 0.01f

#define NBK 8                // pass-A dst buckets
#define BROW 12500           // nodes per bucket
#define BCAP 408000          // per-bucket edge capacity
#define BIN_SEG 4096         // edges per k_bin block
#define E4 (N_EDGES / 4)

#define NBIN 400             // total bins (50 per bucket)
#define BIN_N 250            // nodes per bin
#define CAP2 8704            // per-bin edge capacity (8000 avg + ~8 sigma)
#define CAP2R 10752          // per-bin padded CSR window

typedef _Float16 f16;
typedef int  iv4 __attribute__((ext_vector_type(4)));

static __device__ __forceinline__ float lrelu(float v) {
    return v > 0.0f ? v : SLOPE * v;
}

// ---- init: zero gsum/gcnt, bin cursors, zero rows (replaces 4 memsets) ----
__global__ void k_init(float* __restrict__ gz, int* __restrict__ bz,
                       f16* __restrict__ t2z, f16* __restrict__ sxz) {
    int i = blockIdx.x * blockDim.x + threadIdx.x;
    if (i < N_GRAPHS * H2 + N_GRAPHS) gz[i] = 0.0f;
    if (i < NBK + NBIN + 8) bz[i] = 0;
    if (i < H2) t2z[i] = (f16)0.0f;
    if (i < 8) sxz[i] = (f16)0.0f;
}

// ---- pass A: bin edges by dst bucket, code = src<<14 | dst_local ----
__global__ void k_bin(const int* __restrict__ src, const int* __restrict__ dst,
                      int* __restrict__ bcur, unsigned* __restrict__ benc) {
    __shared__ int cnt[NBK], base[NBK], lcur[NBK];
    int tid = threadIdx.x;
    if (tid < NBK) cnt[tid] = 0;
    __syncthreads();
    const iv4* s4 = (const iv4*)src;
    const iv4* d4 = (const iv4*)dst;
    int i0 = blockIdx.x * (BIN_SEG / 4);
#pragma unroll
    for (int k = 0; k < 4; ++k) {
        int i4 = i0 + tid + k * 256;
        if (i4 < E4) {
            iv4 v = __builtin_nontemporal_load(d4 + i4);
            atomicAdd(&cnt[v.x / BROW], 1);
            atomicAdd(&cnt[v.y / BROW], 1);
            atomicAdd(&cnt[v.z / BROW], 1);
            atomicAdd(&cnt[v.w / BROW], 1);
        }
    }
    __syncthreads();
    if (tid < NBK) { base[tid] = atomicAdd(&bcur[tid], cnt[tid]); lcur[tid] = 0; }
    __syncthreads();
#pragma unroll
    for (int k = 0; k < 4; ++k) {
        int i4 = i0 + tid + k * 256;
        if (i4 < E4) {
            iv4 dv = __builtin_nontemporal_load(d4 + i4);
            iv4 sv = __builtin_nontemporal_load(s4 + i4);
            int b, p;
            b = dv.x / BROW; p = atomicAdd(&lcur[b], 1);
            benc[(long long)b * BCAP + base[b] + p] = ((unsigned)sv.x << 14) | (unsigned)(dv.x - b * BROW);
            b = dv.y / BROW; p = atomicAdd(&lcur[b], 1);
            benc[(long long)b * BCAP + base[b] + p] = ((unsigned)sv.y << 14) | (unsigned)(dv.y - b * BROW);
            b = dv.z / BROW; p = atomicAdd(&lcur[b], 1);
            benc[(long long)b * BCAP + base[b] + p] = ((unsigned)sv.z << 14) | (unsigned)(dv.z - b * BROW);
            b = dv.w / BROW; p = atomicAdd(&lcur[b], 1);
            benc[(long long)b * BCAP + base[b] + p] = ((unsigned)sv.w << 14) | (unsigned)(dv.w - b * BROW);
        }
    }
}

// ---- pass B: bucket -> 50 sub-bins of 250 nodes, code2 = src<<8 | r ----
__global__ void k_binB(const unsigned* __restrict__ benc, const int* __restrict__ bcur,
                       int* __restrict__ bcur2, unsigned* __restrict__ benc2) {
    __shared__ int hist[50], base[50], lcur[50];
    int bk = blockIdx.x & (NBK - 1);
    int grp = blockIdx.x >> 3;           // 0..127
    const int NG = 128;
    int cnt = bcur[bk];
    int chunk = (cnt + NG - 1) / NG;
    int lo = grp * chunk;
    int hi = lo + chunk; if (hi > cnt) hi = cnt;
    const unsigned* p = benc + (long long)bk * BCAP;
    int tid = threadIdx.x;
    if (tid < 50) hist[tid] = 0;
    __syncthreads();
    for (int i = lo + tid; i < hi; i += 256)
        atomicAdd(&hist[(int)(__builtin_nontemporal_load(p + i) & 0x3FFFu) / BIN_N], 1);
    __syncthreads();
    if (tid < 50) {
        base[tid] = atomicAdd(&bcur2[bk * 50 + tid], hist[tid]);
        lcur[tid] = 0;
    }
    __syncthreads();
    for (int i = lo + tid; i < hi; i += 256) {
        unsigned c = p[i];
        int dl = (int)(c & 0x3FFFu);
        int q = dl / BIN_N;
        int r = dl - q * BIN_N;
        int pos = atomicAdd(&lcur[q], 1);
        benc2[(long long)(bk * 50 + q) * CAP2 + base[q] + pos] = ((c >> 14) << 8) | (unsigned)r;
    }
}

// ---- per-bin LDS counting sort -> windowed CSR + deg/dis/sx ----
__global__ void k_sort(const unsigned* __restrict__ benc2, const int* __restrict__ bcur2,
                       const float* __restrict__ x,
                       int* __restrict__ csr, int* __restrict__ obeg, int* __restrict__ oend,
                       float* __restrict__ dis, f16* __restrict__ sx) {
    __shared__ int hist[256];
    __shared__ int scn[256];
    __shared__ int lcur[256];
    int bin = blockIdx.x;
    int tid = threadIdx.x;
    hist[tid] = 0;
    __syncthreads();
    int cnt = bcur2[bin];
    const unsigned* p = benc2 + (long long)bin * CAP2;
    for (int i = tid; i < cnt; i += 256)
        atomicAdd(&hist[p[i] & 0xFFu], 1);
    __syncthreads();
    int deg = hist[tid];
    int pad = (deg + 7) & ~7;
    scn[tid] = pad;
    __syncthreads();
    for (int off = 1; off < 256; off <<= 1) {
        int v = 0;
        if (tid >= off) v = scn[tid - off];
        __syncthreads();
        if (tid >= off) scn[tid] += v;
        __syncthreads();
    }
    int excl = scn[tid] - pad;               // exclusive scan of padded degs
    int gbase = bin * CAP2R;
    lcur[tid] = gbase + excl;
    if (tid < BIN_N) {
        int n = bin * BIN_N + tid;
        obeg[n] = gbase + excl;
        oend[n] = gbase + excl + pad;
        float dn = rsqrtf((float)(deg + 1));
        dis[n] = dn;
#pragma unroll
        for (int j = 0; j < IN_F; ++j)
            sx[n * 8 + j] = (f16)(x[n * IN_F + j] * dn);
        sx[n * 8 + 6] = (f16)0.0f;
        sx[n * 8 + 7] = (f16)0.0f;
    }
    __syncthreads();
    for (int i = tid; i < cnt; i += 256) {
        unsigned c = p[i];
        int pos = atomicAdd(&lcur[c & 0xFFu], 1);
        csr[pos] = (int)(c >> 8);
    }
    __syncthreads();
    if (tid < BIN_N) {
        int end = gbase + excl + pad;
        for (int j = lcur[tid]; j < end; ++j) csr[j] = N_NODES;   // zero-row pad
    }
}

// ---- fused layer 1: gather(sx) -> h1 (LDS) -> t2, 32 nodes/block ----
__global__ void k_l1(const f16* __restrict__ sx, const int* __restrict__ obeg,
                     const int* __restrict__ oend, const int* __restrict__ csr,
                     const float* __restrict__ W1, const float* __restrict__ b1,
                     const float* __restrict__ W2, const float* __restrict__ dis,
                     f16* __restrict__ t2) {
    __shared__ float sW1[IN_F * H1];
    __shared__ float sb1[H1];
    __shared__ float sW2[H1 * H2];
    __shared__ float sagg[32][9];       // +1 pad: avoid bank conflicts
    __shared__ float sh1[32][H1 + 1];   // +1 pad
    __shared__ float sdis[32];
    int tid = threadIdx.x;
    for (int i = tid; i < IN_F * H1; i += 256) sW1[i] = W1[i];
    if (tid < H1) sb1[tid] = b1[tid];
    for (int i = tid; i < H1 * H2; i += 256) sW2[i] = W2[i];
    int loc = tid >> 3;        // 0..31
    int f = tid & 7;
    int n = blockIdx.x * 32 + loc;      // N divisible by 32
    // stage 1: gather
    float acc = (float)sx[(n << 3) + f];
    int b = obeg[n], e = oend[n];
    for (int j = b; j < e; j += 8) {
        const iv4* p = (const iv4*)(csr + j);
        iv4 ia = __builtin_nontemporal_load(p);
        iv4 ib = __builtin_nontemporal_load(p + 1);
        float v0 = (float)sx[(ia.x << 3) + f], v1 = (float)sx[(ia.y << 3) + f];
        float v2 = (float)sx[(ia.z << 3) + f], v3 = (float)sx[(ia.w << 3) + f];
        float v4 = (float)sx[(ib.x << 3) + f], v5 = (float)sx[(ib.y << 3) + f];
        float v6 = (float)sx[(ib.z << 3) + f], v7 = (float)sx[(ib.w << 3) + f];
        acc += ((v0 + v1) + (v2 + v3)) + ((v4 + v5) + (v6 + v7));
    }
    sagg[loc][f] = acc;
    if (f == 0) sdis[loc] = dis[n];
    __syncthreads();
    // stage 2: h1 = lrelu(dis*(agg@W1)+b1); each lane does 8 features
    float dn = sdis[loc];
#pragma unroll
    for (int q = 0; q < 8; ++q) {
        int k = f * 8 + q;
        float s = 0.0f;
#pragma unroll
        for (int j = 0; j < IN_F; ++j) s += sagg[loc][j] * sW1[j * H1 + k];
        sh1[loc][k] = lrelu(s * dn + sb1[k]);
    }
    __syncthreads();
    // stage 3: t2 = dis*(h1@W2); each lane does 4 features, one 8B store
    float r[4];
#pragma unroll
    for (int q = 0; q < 4; ++q) {
        int f2 = f * 4 + q;
        float s = 0.0f;
#pragma unroll
        for (int k = 0; k < H1; ++k) s += sh1[loc][k] * sW2[k * H2 + f2];
        r[q] = s * dn;
    }
    union { ushort4 u; f16 h[4]; } pk;
    pk.h[0] = (f16)r[0]; pk.h[1] = (f16)r[1]; pk.h[2] = (f16)r[2]; pk.h[3] = (f16)r[3];
    *((ushort4*)(t2 + n * H2 + f * 4)) = pk.u;
}

// agg2 gather (unroll x16, nt csr) + lrelu + LDS-deduped mean-pool
__global__ void k_gather2(const f16* __restrict__ t2, const int* __restrict__ obeg,
                          const int* __restrict__ oend, const int* __restrict__ csr,
                          const float* __restrict__ dis, const float* __restrict__ b2,
                          const int* __restrict__ batch,
                          float* __restrict__ gsum, float* __restrict__ gcnt) {
    __shared__ float sv[8][H2];
    __shared__ int sg[8];
    int idx = blockIdx.x * blockDim.x + threadIdx.x;
    int n = idx >> 5;
    int f = idx & 31;
    float acc = (float)t2[(n << 5) + f];
    int b = obeg[n], e = oend[n];
    int j = b;
    for (; j + 16 <= e; j += 16) {
        const iv4* p = (const iv4*)(csr + j);
        iv4 ia = __builtin_nontemporal_load(p);
        iv4 ib = __builtin_nontemporal_load(p + 1);
        iv4 ic = __builtin_nontemporal_load(p + 2);
        iv4 id = __builtin_nontemporal_load(p + 3);
        float v0 = (float)t2[(ia.x << 5) + f], v1 = (float)t2[(ia.y << 5) + f];
        float v2 = (float)t2[(ia.z << 5) + f], v3 = (float)t2[(ia.w << 5) + f];
        float v4 = (float)t2[(ib.x << 5) + f], v5 = (float)t2[(ib.y << 5) + f];
        float v6 = (float)t2[(ib.z << 5) + f], v7 = (float)t2[(ib.w << 5) + f];
        float v8 = (float)t2[(ic.x << 5) + f], v9 = (float)t2[(ic.y << 5) + f];
        float va = (float)t2[(ic.z << 5) + f], vb = (float)t2[(ic.w << 5) + f];
        float vc = (float)t2[(id.x << 5) + f], vd = (float)t2[(id.y << 5) + f];
        float ve = (float)t2[(id.z << 5) + f], vf = (float)t2[(id.w << 5) + f];
        acc += (((v0 + v1) + (v2 + v3)) + ((v4 + v5) + (v6 + v7)))
             + (((v8 + v9) + (va + vb)) + ((vc + vd) + (ve + vf)));
    }
    if (j < e) {
        const iv4* p = (const iv4*)(csr + j);
        iv4 ia = __builtin_nontemporal_load(p);
        iv4 ib = __builtin_nontemporal_load(p + 1);
        float v0 = (float)t2[(ia.x << 5) + f], v1 = (float)t2[(ia.y << 5) + f];
        float v2 = (float)t2[(ia.z << 5) + f], v3 = (float)t2[(ia.w << 5) + f];
        float v4 = (float)t2[(ib.x << 5) + f], v5 = (float)t2[(ib.y << 5) + f];
        float v6 = (float)t2[(ib.z << 5) + f], v7 = (float)t2[(ib.w << 5) + f];
        acc += ((v0 + v1) + (v2 + v3)) + ((v4 + v5) + (v6 + v7));
    }
    float v = lrelu(acc * dis[n] + b2[f]);
    int g = batch[n];
    int loc = threadIdx.x >> 5;
    sv[loc][f] = v;
    if (f == 0) sg[loc] = g;
    __syncthreads();
    bool leader = true;
    for (int l = 0; l < loc; ++l) leader &= (sg[l] != g);
    if (leader) {
        float s = v;
        float c = 1.0f;
        for (int l = loc + 1; l < 8; ++l)
            if (sg[l] == g) { s += sv[l][f]; c += 1.0f; }
        atomicAdd(&gsum[g * H2 + f], s);
        if (f == 0) atomicAdd(&gcnt[g], c);
    }
}

__global__ void k_final(const float* __restrict__ gsum, const float* __restrict__ gcnt,
                        const float* __restrict__ Wlin, const float* __restrict__ blin,
                        float* __restrict__ out) {
    int idx = blockIdx.x * blockDim.x + threadIdx.x;
    if (idx >= N_GRAPHS * 2) return;
    int g = idx >> 1;
    int t = idx & 1;
    float inv = 1.0f / fmaxf(gcnt[g], 1.0f);
    float s = blin[t];
#pragma unroll
    for (int ff = 0; ff < H2; ++ff)
        s += gsum[g * H2 + ff] * inv * Wlin[ff * 2 + t];
    out[idx] = s;
}

static inline int cdiv(long long a, int b) { return (int)((a + b - 1) / b); }

extern "C" void kernel_launch(void* const* d_in, const int* in_sizes, int n_in,
                              void* d_out, int out_size, void* d_ws, size_t ws_size,
                              hipStream_t stream) {
    const float* x    = (const float*)d_in[0];
    const int*   ei   = (const int*)d_in[1];
    const int*   batch= (const int*)d_in[2];
    const float* W1   = (const float*)d_in[3];
    const float* b1   = (const float*)d_in[4];
    const float* W2   = (const float*)d_in[5];
    const float* b2   = (const float*)d_in[6];
    const float* Wlin = (const float*)d_in[7];
    const float* blin = (const float*)d_in[8];
    float* out = (float*)d_out;

    const int* src = ei;
    const int* dst = ei + N_EDGES;

    // ---- workspace layout ----
    f16*   t2   = (f16*)d_ws;                           // 32*(N+1) fp16
    f16*   sx   = t2 + 32LL * (N_NODES + 1);            // 8*(N+1) fp16
    float* dis  = (float*)(sx + 8LL * (N_NODES + 1));   // N f32
    float* gsum = dis + N_NODES;                        // 32G
    float* gcnt = gsum + (long long)N_GRAPHS * H2;      // G
    size_t ioff = ((size_t)(gcnt + N_GRAPHS) + 15) & ~(size_t)15;
    int*  bcur    = (int*)ioff;                         // NBK
    int*  bcur2   = bcur + NBK;                         // NBIN (+pad)
    int*  obeg    = bcur2 + NBIN + 8;                   // N
    int*  oend    = obeg + N_NODES;                     // N
    unsigned* benc  = (unsigned*)(oend + N_NODES);      // NBK*BCAP
    unsigned* benc2 = benc + (long long)NBK * BCAP;     // NBIN*CAP2
    int*  csr      = (int*)(benc2 + (long long)NBIN * CAP2);  // NBIN*CAP2R

    const int B = 256;

    k_init<<<cdiv(N_GRAPHS * H2 + N_GRAPHS, B), B, 0, stream>>>(
        gsum, bcur, t2 + 32LL * N_NODES, sx + 8LL * N_NODES);

    k_bin<<<cdiv(N_EDGES, BIN_SEG), B, 0, stream>>>(src, dst, bcur, benc);
    k_binB<<<1024, B, 0, stream>>>(benc, bcur, bcur2, benc2);
    k_sort<<<NBIN, B, 0, stream>>>(benc2, bcur2, x, csr, obeg, oend, dis, sx);

    k_l1<<<N_NODES / 32, B, 0, stream>>>(sx, obeg, oend, csr, W1, b1, W2, dis, t2);
    k_gather2<<<cdiv((long long)N_NODES * H2, B), B, 0, stream>>>(t2, obeg, oend, csr, dis,
                                                                  b2, batch, gsum, gcnt);
    k_final<<<cdiv(N_GRAPHS * 2, B), B, 0, stream>>>(gsum, gcnt, Wlin, blin, out);
}

// Round 13
// 153.271 us; speedup vs baseline: 6.1527x; 1.1530x over previous
//
#include <hip/hip_runtime.h>

// GCN forward, round 13: packed-dword gathers (16 lanes/node for layer 2,
// 4 lanes/node for layer 1 stage 1) — halves VMEM instruction count of the
// latency-bound gather kernels.
//
//   dis[n] = rsqrt(deg_in[n] + 1)
//   layer1: aggx[n] = sx[n] + sum_{s->n} sx[s],  sx = (x*dis) fp16 [8-padded]
//           h1[n]   = lrelu(dis[n]*(aggx[n] @ W1) + b1)   [64] (LDS only)
//   layer2: t2[n]   = dis[n]*(h1[n] @ W2)  fp16            [32]
//           h2[n]   = lrelu(dis[n]*(t2[n] + sum t2[s]) + b2)
//   pool:   gsum[batch[n]] += h2[n];  out = (gsum/cnt) @ Wlin + blin

#define N_NODES 100000
#define N_EDGES 3200000
#define N_GRAPHS 1024
#define IN_F 6
#define H1 64
#define H2 32
#define SLOPE 0.01f

#define NBK 8                // pass-A dst buckets
#define BROW 12500           // nodes per bucket
#define BCAP 408000          // per-bucket edge capacity
#define BIN_SEG 4096         // edges per k_bin block
#define E4 (N_EDGES / 4)

#define NBIN 400             // total bins (50 per bucket)
#define BIN_N 250            // nodes per bin
#define CAP2 8704            // per-bin edge capacity (8000 avg + ~8 sigma)
#define CAP2R 10752          // per-bin padded CSR window

typedef _Float16 f16;
typedef int  iv4 __attribute__((ext_vector_type(4)));

static __device__ __forceinline__ float lrelu(float v) {
    return v > 0.0f ? v : SLOPE * v;
}

static __device__ __forceinline__ void upk(unsigned w, float& a, float& b) {
    union { unsigned u; f16 h[2]; } cv; cv.u = w;
    a = (float)cv.h[0]; b = (float)cv.h[1];
}

// ---- init: zero gsum/gcnt, bin cursors, zero rows ----
__global__ void k_init(float* __restrict__ gz, int* __restrict__ bz,
                       f16* __restrict__ t2z, f16* __restrict__ sxz) {
    int i = blockIdx.x * blockDim.x + threadIdx.x;
    if (i < N_GRAPHS * H2 + N_GRAPHS) gz[i] = 0.0f;
    if (i < NBK + NBIN + 8) bz[i] = 0;
    if (i < H2) t2z[i] = (f16)0.0f;
    if (i < 8) sxz[i] = (f16)0.0f;
}

// ---- pass A: bin edges by dst bucket, code = src<<14 | dst_local ----
__global__ void k_bin(const int* __restrict__ src, const int* __restrict__ dst,
                      int* __restrict__ bcur, unsigned* __restrict__ benc) {
    __shared__ int cnt[NBK], base[NBK], lcur[NBK];
    int tid = threadIdx.x;
    if (tid < NBK) cnt[tid] = 0;
    __syncthreads();
    const iv4* s4 = (const iv4*)src;
    const iv4* d4 = (const iv4*)dst;
    int i0 = blockIdx.x * (BIN_SEG / 4);
#pragma unroll
    for (int k = 0; k < 4; ++k) {
        int i4 = i0 + tid + k * 256;
        if (i4 < E4) {
            iv4 v = __builtin_nontemporal_load(d4 + i4);
            atomicAdd(&cnt[v.x / BROW], 1);
            atomicAdd(&cnt[v.y / BROW], 1);
            atomicAdd(&cnt[v.z / BROW], 1);
            atomicAdd(&cnt[v.w / BROW], 1);
        }
    }
    __syncthreads();
    if (tid < NBK) { base[tid] = atomicAdd(&bcur[tid], cnt[tid]); lcur[tid] = 0; }
    __syncthreads();
#pragma unroll
    for (int k = 0; k < 4; ++k) {
        int i4 = i0 + tid + k * 256;
        if (i4 < E4) {
            iv4 dv = __builtin_nontemporal_load(d4 + i4);
            iv4 sv = __builtin_nontemporal_load(s4 + i4);
            int b, p;
            b = dv.x / BROW; p = atomicAdd(&lcur[b], 1);
            benc[(long long)b * BCAP + base[b] + p] = ((unsigned)sv.x << 14) | (unsigned)(dv.x - b * BROW);
            b = dv.y / BROW; p = atomicAdd(&lcur[b], 1);
            benc[(long long)b * BCAP + base[b] + p] = ((unsigned)sv.y << 14) | (unsigned)(dv.y - b * BROW);
            b = dv.z / BROW; p = atomicAdd(&lcur[b], 1);
            benc[(long long)b * BCAP + base[b] + p] = ((unsigned)sv.z << 14) | (unsigned)(dv.z - b * BROW);
            b = dv.w / BROW; p = atomicAdd(&lcur[b], 1);
            benc[(long long)b * BCAP + base[b] + p] = ((unsigned)sv.w << 14) | (unsigned)(dv.w - b * BROW);
        }
    }
}

// ---- pass B: bucket -> 50 sub-bins of 250 nodes, code2 = src<<8 | r ----
__global__ void k_binB(const unsigned* __restrict__ benc, const int* __restrict__ bcur,
                       int* __restrict__ bcur2, unsigned* __restrict__ benc2) {
    __shared__ int hist[50], base[50], lcur[50];
    int bk = blockIdx.x & (NBK - 1);
    int grp = blockIdx.x >> 3;           // 0..127
    const int NG = 128;
    int cnt = bcur[bk];
    int chunk = (cnt + NG - 1) / NG;
    int lo = grp * chunk;
    int hi = lo + chunk; if (hi > cnt) hi = cnt;
    const unsigned* p = benc + (long long)bk * BCAP;
    int tid = threadIdx.x;
    if (tid < 50) hist[tid] = 0;
    __syncthreads();
    for (int i = lo + tid; i < hi; i += 256)
        atomicAdd(&hist[(int)(__builtin_nontemporal_load(p + i) & 0x3FFFu) / BIN_N], 1);
    __syncthreads();
    if (tid < 50) {
        base[tid] = atomicAdd(&bcur2[bk * 50 + tid], hist[tid]);
        lcur[tid] = 0;
    }
    __syncthreads();
    for (int i = lo + tid; i < hi; i += 256) {
        unsigned c = p[i];
        int dl = (int)(c & 0x3FFFu);
        int q = dl / BIN_N;
        int r = dl - q * BIN_N;
        int pos = atomicAdd(&lcur[q], 1);
        benc2[(long long)(bk * 50 + q) * CAP2 + base[q] + pos] = ((c >> 14) << 8) | (unsigned)r;
    }
}

// ---- per-bin LDS counting sort -> windowed CSR + deg/dis/sx ----
__global__ void k_sort(const unsigned* __restrict__ benc2, const int* __restrict__ bcur2,
                       const float* __restrict__ x,
                       int* __restrict__ csr, int* __restrict__ obeg, int* __restrict__ oend,
                       float* __restrict__ dis, f16* __restrict__ sx) {
    __shared__ int hist[256];
    __shared__ int scn[256];
    __shared__ int lcur[256];
    int bin = blockIdx.x;
    int tid = threadIdx.x;
    hist[tid] = 0;
    __syncthreads();
    int cnt = bcur2[bin];
    const unsigned* p = benc2 + (long long)bin * CAP2;
    for (int i = tid; i < cnt; i += 256)
        atomicAdd(&hist[p[i] & 0xFFu], 1);
    __syncthreads();
    int deg = hist[tid];
    int pad = (deg + 7) & ~7;
    scn[tid] = pad;
    __syncthreads();
    for (int off = 1; off < 256; off <<= 1) {
        int v = 0;
        if (tid >= off) v = scn[tid - off];
        __syncthreads();
        if (tid >= off) scn[tid] += v;
        __syncthreads();
    }
    int excl = scn[tid] - pad;               // exclusive scan of padded degs
    int gbase = bin * CAP2R;
    lcur[tid] = gbase + excl;
    if (tid < BIN_N) {
        int n = bin * BIN_N + tid;
        obeg[n] = gbase + excl;
        oend[n] = gbase + excl + pad;
        float dn = rsqrtf((float)(deg + 1));
        dis[n] = dn;
#pragma unroll
        for (int j = 0; j < IN_F; ++j)
            sx[n * 8 + j] = (f16)(x[n * IN_F + j] * dn);
        sx[n * 8 + 6] = (f16)0.0f;
        sx[n * 8 + 7] = (f16)0.0f;
    }
    __syncthreads();
    for (int i = tid; i < cnt; i += 256) {
        unsigned c = p[i];
        int pos = atomicAdd(&lcur[c & 0xFFu], 1);
        csr[pos] = (int)(c >> 8);
    }
    __syncthreads();
    if (tid < BIN_N) {
        int end = gbase + excl + pad;
        for (int j = lcur[tid]; j < end; ++j) csr[j] = N_NODES;   // zero-row pad
    }
}

// ---- fused layer 1: gather(sx dwords) -> h1 (LDS) -> t2 ----
// 64 nodes/block, 4 lanes/node; each lane owns one dword (2 fp16 feats).
__global__ void k_l1(const unsigned* __restrict__ sxu, const int* __restrict__ obeg,
                     const int* __restrict__ oend, const int* __restrict__ csr,
                     const float* __restrict__ W1, const float* __restrict__ b1,
                     const float* __restrict__ W2, const float* __restrict__ dis,
                     f16* __restrict__ t2) {
    __shared__ float sW1[IN_F * H1];
    __shared__ float sb1[H1];
    __shared__ float sW2[H1 * H2];
    __shared__ float sagg[64][9];       // +pad
    __shared__ float sh1[64][H1 + 1];   // +pad
    __shared__ float sdis[64];
    int tid = threadIdx.x;
    for (int i = tid; i < IN_F * H1; i += 256) sW1[i] = W1[i];
    if (tid < H1) sb1[tid] = b1[tid];
    for (int i = tid; i < H1 * H2; i += 256) sW2[i] = W2[i];
    int loc = tid >> 2;        // 0..63
    int f = tid & 3;           // dword index within 16B row
    int n = blockIdx.x * 64 + loc;
    bool ok = n < N_NODES;
    if (ok) {
        float acc0, acc1;
        upk(sxu[(n << 2) + f], acc0, acc1);
        int b = obeg[n], e = oend[n];
        for (int j = b; j < e; j += 8) {
            const iv4* p = (const iv4*)(csr + j);
            iv4 ia = p[0], ib = p[1];
            unsigned w[8];
            w[0] = sxu[(ia.x << 2) + f]; w[1] = sxu[(ia.y << 2) + f];
            w[2] = sxu[(ia.z << 2) + f]; w[3] = sxu[(ia.w << 2) + f];
            w[4] = sxu[(ib.x << 2) + f]; w[5] = sxu[(ib.y << 2) + f];
            w[6] = sxu[(ib.z << 2) + f]; w[7] = sxu[(ib.w << 2) + f];
            float fa[8], fb[8];
#pragma unroll
            for (int q = 0; q < 8; ++q) upk(w[q], fa[q], fb[q]);
            acc0 += ((fa[0]+fa[1])+(fa[2]+fa[3])) + ((fa[4]+fa[5])+(fa[6]+fa[7]));
            acc1 += ((fb[0]+fb[1])+(fb[2]+fb[3])) + ((fb[4]+fb[5])+(fb[6]+fb[7]));
        }
        sagg[loc][2*f]   = acc0;
        sagg[loc][2*f+1] = acc1;
        if (f == 0) sdis[loc] = dis[n];
    }
    __syncthreads();
    float dn = sdis[loc];
    // stage 2: h1 = lrelu(dis*(agg@W1)+b1); each lane does 16 features
#pragma unroll
    for (int q = 0; q < 16; ++q) {
        int k = (f << 4) + q;
        float s = 0.0f;
#pragma unroll
        for (int j = 0; j < IN_F; ++j) s += sagg[loc][j] * sW1[j * H1 + k];
        sh1[loc][k] = lrelu(s * dn + sb1[k]);
    }
    __syncthreads();
    // stage 3: t2 = dis*(h1@W2); each lane does 8 features, one 16B store
    float r[8];
#pragma unroll
    for (int q = 0; q < 8; ++q) {
        int f2 = (f << 3) + q;
        float s = 0.0f;
#pragma unroll
        for (int k = 0; k < H1; ++k) s += sh1[loc][k] * sW2[k * H2 + f2];
        r[q] = s * dn;
    }
    if (ok) {
        union { uint4 u; f16 h[8]; } pk;
#pragma unroll
        for (int q = 0; q < 8; ++q) pk.h[q] = (f16)r[q];
        *((uint4*)(t2 + n * H2 + f * 8)) = pk.u;
    }
}

// ---- layer-2 gather: 16 lanes/node, dword-packed t2 reads ----
__global__ void k_gather2(const unsigned* __restrict__ t2u, const int* __restrict__ obeg,
                          const int* __restrict__ oend, const int* __restrict__ csr,
                          const float* __restrict__ dis, const float* __restrict__ b2,
                          const int* __restrict__ batch,
                          float* __restrict__ gsum, float* __restrict__ gcnt) {
    __shared__ float sv[16][H2];
    __shared__ int sg[16];
    int idx = blockIdx.x * blockDim.x + threadIdx.x;
    int n = idx >> 4;          // 16 nodes per 256-thread block
    int f = idx & 15;          // feature pair {2f, 2f+1}
    float acc0, acc1;
    upk(t2u[(n << 4) + f], acc0, acc1);
    int b = obeg[n], e = oend[n];
    int j = b;
    for (; j + 16 <= e; j += 16) {
        const iv4* p = (const iv4*)(csr + j);
        iv4 ia = p[0], ib = p[1], ic = p[2], id = p[3];
        unsigned w[16];
        w[0]  = t2u[(ia.x << 4) + f]; w[1]  = t2u[(ia.y << 4) + f];
        w[2]  = t2u[(ia.z << 4) + f]; w[3]  = t2u[(ia.w << 4) + f];
        w[4]  = t2u[(ib.x << 4) + f]; w[5]  = t2u[(ib.y << 4) + f];
        w[6]  = t2u[(ib.z << 4) + f]; w[7]  = t2u[(ib.w << 4) + f];
        w[8]  = t2u[(ic.x << 4) + f]; w[9]  = t2u[(ic.y << 4) + f];
        w[10] = t2u[(ic.z << 4) + f]; w[11] = t2u[(ic.w << 4) + f];
        w[12] = t2u[(id.x << 4) + f]; w[13] = t2u[(id.y << 4) + f];
        w[14] = t2u[(id.z << 4) + f]; w[15] = t2u[(id.w << 4) + f];
        float fa[16], fb[16];
#pragma unroll
        for (int q = 0; q < 16; ++q) upk(w[q], fa[q], fb[q]);
        acc0 += (((fa[0]+fa[1])+(fa[2]+fa[3])) + ((fa[4]+fa[5])+(fa[6]+fa[7])))
              + (((fa[8]+fa[9])+(fa[10]+fa[11])) + ((fa[12]+fa[13])+(fa[14]+fa[15])));
        acc1 += (((fb[0]+fb[1])+(fb[2]+fb[3])) + ((fb[4]+fb[5])+(fb[6]+fb[7])))
              + (((fb[8]+fb[9])+(fb[10]+fb[11])) + ((fb[12]+fb[13])+(fb[14]+fb[15])));
    }
    if (j < e) {   // one remaining 8-chunk (lists are 8-aligned)
        const iv4* p = (const iv4*)(csr + j);
        iv4 ia = p[0], ib = p[1];
        unsigned w[8];
        w[0] = t2u[(ia.x << 4) + f]; w[1] = t2u[(ia.y << 4) + f];
        w[2] = t2u[(ia.z << 4) + f]; w[3] = t2u[(ia.w << 4) + f];
        w[4] = t2u[(ib.x << 4) + f]; w[5] = t2u[(ib.y << 4) + f];
        w[6] = t2u[(ib.z << 4) + f]; w[7] = t2u[(ib.w << 4) + f];
        float fa[8], fb[8];
#pragma unroll
        for (int q = 0; q < 8; ++q) upk(w[q], fa[q], fb[q]);
        acc0 += ((fa[0]+fa[1])+(fa[2]+fa[3])) + ((fa[4]+fa[5])+(fa[6]+fa[7]));
        acc1 += ((fb[0]+fb[1])+(fb[2]+fb[3])) + ((fb[4]+fb[5])+(fb[6]+fb[7]));
    }
    float dn = dis[n];
    float v0 = lrelu(acc0 * dn + b2[2*f]);
    float v1 = lrelu(acc1 * dn + b2[2*f+1]);
    int g = batch[n];
    int loc = threadIdx.x >> 4;
    sv[loc][2*f]   = v0;
    sv[loc][2*f+1] = v1;
    if (f == 0) sg[loc] = g;
    __syncthreads();
    bool leader = true;
    for (int l = 0; l < loc; ++l) leader &= (sg[l] != g);
    if (leader) {
        float s0 = v0, s1 = v1;
        float c = 1.0f;
        for (int l = loc + 1; l < 16; ++l)
            if (sg[l] == g) { s0 += sv[l][2*f]; s1 += sv[l][2*f+1]; c += 1.0f; }
        atomicAdd(&gsum[g * H2 + 2*f], s0);
        atomicAdd(&gsum[g * H2 + 2*f+1], s1);
        if (f == 0) atomicAdd(&gcnt[g], c);
    }
}

__global__ void k_final(const float* __restrict__ gsum, const float* __restrict__ gcnt,
                        const float* __restrict__ Wlin, const float* __restrict__ blin,
                        float* __restrict__ out) {
    int idx = blockIdx.x * blockDim.x + threadIdx.x;
    if (idx >= N_GRAPHS * 2) return;
    int g = idx >> 1;
    int t = idx & 1;
    float inv = 1.0f / fmaxf(gcnt[g], 1.0f);
    float s = blin[t];
#pragma unroll
    for (int ff = 0; ff < H2; ++ff)
        s += gsum[g * H2 + ff] * inv * Wlin[ff * 2 + t];
    out[idx] = s;
}

static inline int cdiv(long long a, int b) { return (int)((a + b - 1) / b); }

extern "C" void kernel_launch(void* const* d_in, const int* in_sizes, int n_in,
                              void* d_out, int out_size, void* d_ws, size_t ws_size,
                              hipStream_t stream) {
    const float* x    = (const float*)d_in[0];
    const int*   ei   = (const int*)d_in[1];
    const int*   batch= (const int*)d_in[2];
    const float* W1   = (const float*)d_in[3];
    const float* b1   = (const float*)d_in[4];
    const float* W2   = (const float*)d_in[5];
    const float* b2   = (const float*)d_in[6];
    const float* Wlin = (const float*)d_in[7];
    const float* blin = (const float*)d_in[8];
    float* out = (float*)d_out;

    const int* src = ei;
    const int* dst = ei + N_EDGES;

    // ---- workspace layout ----
    f16*   t2   = (f16*)d_ws;                           // 32*(N+1) fp16
    f16*   sx   = t2 + 32LL * (N_NODES + 1);            // 8*(N+1) fp16
    float* dis  = (float*)(sx + 8LL * (N_NODES + 1));   // N f32
    float* gsum = dis + N_NODES;                        // 32G
    float* gcnt = gsum + (long long)N_GRAPHS * H2;      // G
    size_t ioff = ((size_t)(gcnt + N_GRAPHS) + 15) & ~(size_t)15;
    int*  bcur    = (int*)ioff;                         // NBK
    int*  bcur2   = bcur + NBK;                         // NBIN (+pad)
    int*  obeg    = bcur2 + NBIN + 8;                   // N
    int*  oend    = obeg + N_NODES;                     // N
    unsigned* benc  = (unsigned*)(oend + N_NODES);      // NBK*BCAP
    unsigned* benc2 = benc + (long long)NBK * BCAP;     // NBIN*CAP2
    int*  csr      = (int*)(benc2 + (long long)NBIN * CAP2);  // NBIN*CAP2R

    const int B = 256;

    k_init<<<cdiv(N_GRAPHS * H2 + N_GRAPHS, B), B, 0, stream>>>(
        gsum, bcur, t2 + 32LL * N_NODES, sx + 8LL * N_NODES);

    k_bin<<<cdiv(N_EDGES, BIN_SEG), B, 0, stream>>>(src, dst, bcur, benc);
    k_binB<<<1024, B, 0, stream>>>(benc, bcur, bcur2, benc2);
    k_sort<<<NBIN, B, 0, stream>>>(benc2, bcur2, x, csr, obeg, oend, dis, sx);

    k_l1<<<cdiv(N_NODES, 64), B, 0, stream>>>((const unsigned*)sx, obeg, oend, csr,
                                              W1, b1, W2, dis, t2);
    k_gather2<<<cdiv((long long)N_NODES * 16, B), B, 0, stream>>>(
        (const unsigned*)t2, obeg, oend, csr, dis, b2, batch, gsum, gcnt);
    k_final<<<cdiv(N_GRAPHS * 2, B), B, 0, stream>>>(gsum, gcnt, Wlin, blin, out);
}

// Round 14
// 151.160 us; speedup vs baseline: 6.2387x; 1.0140x over previous
//
#include <hip/hip_runtime.h>

// GCN forward, round 14: single-pass 400-bin LDS counting sort (replaces the
// 2-level k_bin + k_binB), per-bin LDS sort into windowed CSR, packed-dword
// gathers, fp16 tables.
//
//   dis[n] = rsqrt(deg_in[n] + 1)
//   layer1: aggx[n] = sx[n] + sum_{s->n} sx[s],  sx = (x*dis) fp16 [8-padded]
//           h1[n]   = lrelu(dis[n]*(aggx[n] @ W1) + b1)   [64] (LDS only)
//   layer2: t2[n]   = dis[n]*(h1[n] @ W2)  fp16            [32]
//           h2[n]   = lrelu(dis[n]*(t2[n] + sum t2[s]) + b2)
//   pool:   gsum[batch[n]] += h2[n];  out = (gsum/cnt) @ Wlin + blin

#define N_NODES 100000
#define N_EDGES 3200000
#define N_GRAPHS 1024
#define IN_F 6
#define H1 64
#define H2 32
#define SLOPE 0.01f

#define NBIN 400             // bins of 250 dst nodes
#define BIN_N 250
#define CAP2 8704            // per-bin edge capacity (8000 avg + ~8 sigma)
#define CAP2R 10752          // per-bin padded CSR window

#define SEG 4096             // edges per k_bin400 block
#define NSEGB ((N_EDGES + SEG - 1) / SEG)   // 782

typedef _Float16 f16;
typedef int  iv4 __attribute__((ext_vector_type(4)));

static __device__ __forceinline__ float lrelu(float v) {
    return v > 0.0f ? v : SLOPE * v;
}

static __device__ __forceinline__ void upk(unsigned w, float& a, float& b) {
    union { unsigned u; f16 h[2]; } cv; cv.u = w;
    a = (float)cv.h[0]; b = (float)cv.h[1];
}

// ---- init: zero gsum/gcnt, bin cursors, zero rows ----
__global__ void k_init(float* __restrict__ gz, int* __restrict__ bz,
                       f16* __restrict__ t2z, f16* __restrict__ sxz) {
    int i = blockIdx.x * blockDim.x + threadIdx.x;
    if (i < N_GRAPHS * H2 + N_GRAPHS) gz[i] = 0.0f;
    if (i < NBIN + 16) bz[i] = 0;
    if (i < H2) t2z[i] = (f16)0.0f;
    if (i < 8) sxz[i] = (f16)0.0f;
}

// ---- single-pass 400-bin counting sort of the edge list ----
// Each block: LDS-histogram its 4096-edge segment over all 400 bins,
// LDS scan, reserve global space (1 atomic per touched bin), LDS scatter
// codes (src<<8 | dst_local), stream runs out contiguously.
__global__ void k_bin400(const int* __restrict__ src, const int* __restrict__ dst,
                         int* __restrict__ bcur2, unsigned* __restrict__ benc2) {
    __shared__ int hist[NBIN];
    __shared__ int lscan[NBIN];
    __shared__ int lcur[NBIN];
    __shared__ int gbase[NBIN];
    __shared__ int scn[512];
    __shared__ unsigned codes[SEG];          // 16 KB
    __shared__ unsigned short bslot[SEG];    // 8 KB
    int tid = threadIdx.x;
    for (int i = tid; i < NBIN; i += 256) hist[i] = 0;
    __syncthreads();
    int e0 = blockIdx.x * SEG;
    int e1 = e0 + SEG; if (e1 > N_EDGES) e1 = N_EDGES;
    int cnt = e1 - e0;
    const iv4* d4 = (const iv4*)dst;
    const iv4* s4 = (const iv4*)src;
    int i40 = e0 >> 2, i41 = e1 >> 2;
    // phase 1: histogram
    for (int i4 = i40 + tid; i4 < i41; i4 += 256) {
        iv4 v = __builtin_nontemporal_load(d4 + i4);
        atomicAdd(&hist[v.x / BIN_N], 1);
        atomicAdd(&hist[v.y / BIN_N], 1);
        atomicAdd(&hist[v.z / BIN_N], 1);
        atomicAdd(&hist[v.w / BIN_N], 1);
    }
    __syncthreads();
    // phase 2: scan 400 (padded to 512), reserve global space
    scn[tid]       = (tid < NBIN) ? hist[tid] : 0;
    scn[tid + 256] = (tid + 256 < NBIN) ? hist[tid + 256] : 0;
    __syncthreads();
    for (int off = 1; off < 512; off <<= 1) {
        int v0 = (tid >= off) ? scn[tid - off] : 0;
        int v1 = (tid + 256 >= off) ? scn[tid + 256 - off] : 0;
        __syncthreads();
        scn[tid] += v0;
        scn[tid + 256] += v1;
        __syncthreads();
    }
    if (tid < NBIN) {
        int h = hist[tid];
        int ls = scn[tid] - h;          // exclusive
        lscan[tid] = ls;
        lcur[tid] = ls;
        gbase[tid] = h ? atomicAdd(&bcur2[tid], h) : 0;
        for (int j = ls; j < ls + h; ++j) bslot[j] = (unsigned short)tid;
    }
    if (tid + 256 < NBIN) {
        int t = tid + 256;
        int h = hist[t];
        int ls = scn[t] - h;
        lscan[t] = ls;
        lcur[t] = ls;
        gbase[t] = h ? atomicAdd(&bcur2[t], h) : 0;
        for (int j = ls; j < ls + h; ++j) bslot[j] = (unsigned short)t;
    }
    __syncthreads();
    // phase 3: scatter codes into LDS runs
    for (int i4 = i40 + tid; i4 < i41; i4 += 256) {
        iv4 dv = __builtin_nontemporal_load(d4 + i4);
        iv4 sv = __builtin_nontemporal_load(s4 + i4);
        int b, p;
        b = dv.x / BIN_N; p = atomicAdd(&lcur[b], 1);
        codes[p] = ((unsigned)sv.x << 8) | (unsigned)(dv.x - b * BIN_N);
        b = dv.y / BIN_N; p = atomicAdd(&lcur[b], 1);
        codes[p] = ((unsigned)sv.y << 8) | (unsigned)(dv.y - b * BIN_N);
        b = dv.z / BIN_N; p = atomicAdd(&lcur[b], 1);
        codes[p] = ((unsigned)sv.z << 8) | (unsigned)(dv.z - b * BIN_N);
        b = dv.w / BIN_N; p = atomicAdd(&lcur[b], 1);
        codes[p] = ((unsigned)sv.w << 8) | (unsigned)(dv.w - b * BIN_N);
    }
    __syncthreads();
    // phase 4: stream runs out (consecutive slots -> consecutive global)
    for (int slot = tid; slot < cnt; slot += 256) {
        int b = bslot[slot];
        int g = gbase[b] + (slot - lscan[b]);
        benc2[(long long)b * CAP2 + g] = codes[slot];
    }
}

// ---- per-bin LDS counting sort -> windowed CSR + deg/dis/sx ----
__global__ void k_sort(const unsigned* __restrict__ benc2, const int* __restrict__ bcur2,
                       const float* __restrict__ x,
                       int* __restrict__ csr, int* __restrict__ obeg, int* __restrict__ oend,
                       float* __restrict__ dis, f16* __restrict__ sx) {
    __shared__ int hist[256];
    __shared__ int scn[256];
    __shared__ int lcur[256];
    int bin = blockIdx.x;
    int tid = threadIdx.x;
    hist[tid] = 0;
    __syncthreads();
    int cnt = bcur2[bin];
    const unsigned* p = benc2 + (long long)bin * CAP2;
    for (int i = tid; i < cnt; i += 256)
        atomicAdd(&hist[p[i] & 0xFFu], 1);
    __syncthreads();
    int deg = hist[tid];
    int pad = (deg + 7) & ~7;
    scn[tid] = pad;
    __syncthreads();
    for (int off = 1; off < 256; off <<= 1) {
        int v = 0;
        if (tid >= off) v = scn[tid - off];
        __syncthreads();
        if (tid >= off) scn[tid] += v;
        __syncthreads();
    }
    int excl = scn[tid] - pad;               // exclusive scan of padded degs
    int gbase = bin * CAP2R;
    lcur[tid] = gbase + excl;
    if (tid < BIN_N) {
        int n = bin * BIN_N + tid;
        obeg[n] = gbase + excl;
        oend[n] = gbase + excl + pad;
        float dn = rsqrtf((float)(deg + 1));
        dis[n] = dn;
#pragma unroll
        for (int j = 0; j < IN_F; ++j)
            sx[n * 8 + j] = (f16)(x[n * IN_F + j] * dn);
        sx[n * 8 + 6] = (f16)0.0f;
        sx[n * 8 + 7] = (f16)0.0f;
    }
    __syncthreads();
    for (int i = tid; i < cnt; i += 256) {
        unsigned c = p[i];
        int pos = atomicAdd(&lcur[c & 0xFFu], 1);
        csr[pos] = (int)(c >> 8);
    }
    __syncthreads();
    if (tid < BIN_N) {
        int end = gbase + excl + pad;
        for (int j = lcur[tid]; j < end; ++j) csr[j] = N_NODES;   // zero-row pad
    }
}

// ---- fused layer 1: gather(sx dwords) -> h1 (LDS) -> t2 ----
// 64 nodes/block, 4 lanes/node; each lane owns one dword (2 fp16 feats).
__global__ void k_l1(const unsigned* __restrict__ sxu, const int* __restrict__ obeg,
                     const int* __restrict__ oend, const int* __restrict__ csr,
                     const float* __restrict__ W1, const float* __restrict__ b1,
                     const float* __restrict__ W2, const float* __restrict__ dis,
                     f16* __restrict__ t2) {
    __shared__ float sW1[IN_F * H1];
    __shared__ float sb1[H1];
    __shared__ float sW2[H1 * H2];
    __shared__ float sagg[64][9];       // +pad
    __shared__ float sh1[64][H1 + 1];   // +pad
    __shared__ float sdis[64];
    int tid = threadIdx.x;
    for (int i = tid; i < IN_F * H1; i += 256) sW1[i] = W1[i];
    if (tid < H1) sb1[tid] = b1[tid];
    for (int i = tid; i < H1 * H2; i += 256) sW2[i] = W2[i];
    int loc = tid >> 2;        // 0..63
    int f = tid & 3;           // dword index within 16B row
    int n = blockIdx.x * 64 + loc;
    bool ok = n < N_NODES;
    if (ok) {
        float acc0, acc1;
        upk(sxu[(n << 2) + f], acc0, acc1);
        int b = obeg[n], e = oend[n];
        for (int j = b; j < e; j += 8) {
            const iv4* p = (const iv4*)(csr + j);
            iv4 ia = p[0], ib = p[1];
            unsigned w[8];
            w[0] = sxu[(ia.x << 2) + f]; w[1] = sxu[(ia.y << 2) + f];
            w[2] = sxu[(ia.z << 2) + f]; w[3] = sxu[(ia.w << 2) + f];
            w[4] = sxu[(ib.x << 2) + f]; w[5] = sxu[(ib.y << 2) + f];
            w[6] = sxu[(ib.z << 2) + f]; w[7] = sxu[(ib.w << 2) + f];
            float fa[8], fb[8];
#pragma unroll
            for (int q = 0; q < 8; ++q) upk(w[q], fa[q], fb[q]);
            acc0 += ((fa[0]+fa[1])+(fa[2]+fa[3])) + ((fa[4]+fa[5])+(fa[6]+fa[7]));
            acc1 += ((fb[0]+fb[1])+(fb[2]+fb[3])) + ((fb[4]+fb[5])+(fb[6]+fb[7]));
        }
        sagg[loc][2*f]   = acc0;
        sagg[loc][2*f+1] = acc1;
        if (f == 0) sdis[loc] = dis[n];
    }
    __syncthreads();
    float dn = sdis[loc];
    // stage 2: h1 = lrelu(dis*(agg@W1)+b1); each lane does 16 features
#pragma unroll
    for (int q = 0; q < 16; ++q) {
        int k = (f << 4) + q;
        float s = 0.0f;
#pragma unroll
        for (int j = 0; j < IN_F; ++j) s += sagg[loc][j] * sW1[j * H1 + k];
        sh1[loc][k] = lrelu(s * dn + sb1[k]);
    }
    __syncthreads();
    // stage 3: t2 = dis*(h1@W2); each lane does 8 features, one 16B store
    float r[8];
#pragma unroll
    for (int q = 0; q < 8; ++q) {
        int f2 = (f << 3) + q;
        float s = 0.0f;
#pragma unroll
        for (int k = 0; k < H1; ++k) s += sh1[loc][k] * sW2[k * H2 + f2];
        r[q] = s * dn;
    }
    if (ok) {
        union { uint4 u; f16 h[8]; } pk;
#pragma unroll
        for (int q = 0; q < 8; ++q) pk.h[q] = (f16)r[q];
        *((uint4*)(t2 + n * H2 + f * 8)) = pk.u;
    }
}

// ---- layer-2 gather: 16 lanes/node, dword-packed t2 reads ----
__global__ void k_gather2(const unsigned* __restrict__ t2u, const int* __restrict__ obeg,
                          const int* __restrict__ oend, const int* __restrict__ csr,
                          const float* __restrict__ dis, const float* __restrict__ b2,
                          const int* __restrict__ batch,
                          float* __restrict__ gsum, float* __restrict__ gcnt) {
    __shared__ float sv[16][H2];
    __shared__ int sg[16];
    int idx = blockIdx.x * blockDim.x + threadIdx.x;
    int n = idx >> 4;          // 16 nodes per 256-thread block
    int f = idx & 15;          // feature pair {2f, 2f+1}
    float acc0, acc1;
    upk(t2u[(n << 4) + f], acc0, acc1);
    int b = obeg[n], e = oend[n];
    int j = b;
    for (; j + 16 <= e; j += 16) {
        const iv4* p = (const iv4*)(csr + j);
        iv4 ia = p[0], ib = p[1], ic = p[2], id = p[3];
        unsigned w[16];
        w[0]  = t2u[(ia.x << 4) + f]; w[1]  = t2u[(ia.y << 4) + f];
        w[2]  = t2u[(ia.z << 4) + f]; w[3]  = t2u[(ia.w << 4) + f];
        w[4]  = t2u[(ib.x << 4) + f]; w[5]  = t2u[(ib.y << 4) + f];
        w[6]  = t2u[(ib.z << 4) + f]; w[7]  = t2u[(ib.w << 4) + f];
        w[8]  = t2u[(ic.x << 4) + f]; w[9]  = t2u[(ic.y << 4) + f];
        w[10] = t2u[(ic.z << 4) + f]; w[11] = t2u[(ic.w << 4) + f];
        w[12] = t2u[(id.x << 4) + f]; w[13] = t2u[(id.y << 4) + f];
        w[14] = t2u[(id.z << 4) + f]; w[15] = t2u[(id.w << 4) + f];
        float fa[16], fb[16];
#pragma unroll
        for (int q = 0; q < 16; ++q) upk(w[q], fa[q], fb[q]);
        acc0 += (((fa[0]+fa[1])+(fa[2]+fa[3])) + ((fa[4]+fa[5])+(fa[6]+fa[7])))
              + (((fa[8]+fa[9])+(fa[10]+fa[11])) + ((fa[12]+fa[13])+(fa[14]+fa[15])));
        acc1 += (((fb[0]+fb[1])+(fb[2]+fb[3])) + ((fb[4]+fb[5])+(fb[6]+fb[7])))
              + (((fb[8]+fb[9])+(fb[10]+fb[11])) + ((fb[12]+fb[13])+(fb[14]+fb[15])));
    }
    if (j < e) {   // one remaining 8-chunk (lists are 8-aligned)
        const iv4* p = (const iv4*)(csr + j);
        iv4 ia = p[0], ib = p[1];
        unsigned w[8];
        w[0] = t2u[(ia.x << 4) + f]; w[1] = t2u[(ia.y << 4) + f];
        w[2] = t2u[(ia.z << 4) + f]; w[3] = t2u[(ia.w << 4) + f];
        w[4] = t2u[(ib.x << 4) + f]; w[5] = t2u[(ib.y << 4) + f];
        w[6] = t2u[(ib.z << 4) + f]; w[7] = t2u[(ib.w << 4) + f];
        float fa[8], fb[8];
#pragma unroll
        for (int q = 0; q < 8; ++q) upk(w[q], fa[q], fb[q]);
        acc0 += ((fa[0]+fa[1])+(fa[2]+fa[3])) + ((fa[4]+fa[5])+(fa[6]+fa[7]));
        acc1 += ((fb[0]+fb[1])+(fb[2]+fb[3])) + ((fb[4]+fb[5])+(fb[6]+fb[7]));
    }
    float dn = dis[n];
    float v0 = lrelu(acc0 * dn + b2[2*f]);
    float v1 = lrelu(acc1 * dn + b2[2*f+1]);
    int g = batch[n];
    int loc = threadIdx.x >> 4;
    sv[loc][2*f]   = v0;
    sv[loc][2*f+1] = v1;
    if (f == 0) sg[loc] = g;
    __syncthreads();
    bool leader = true;
    for (int l = 0; l < loc; ++l) leader &= (sg[l] != g);
    if (leader) {
        float s0 = v0, s1 = v1;
        float c = 1.0f;
        for (int l = loc + 1; l < 16; ++l)
            if (sg[l] == g) { s0 += sv[l][2*f]; s1 += sv[l][2*f+1]; c += 1.0f; }
        atomicAdd(&gsum[g * H2 + 2*f], s0);
        atomicAdd(&gsum[g * H2 + 2*f+1], s1);
        if (f == 0) atomicAdd(&gcnt[g], c);
    }
}

__global__ void k_final(const float* __restrict__ gsum, const float* __restrict__ gcnt,
                        const float* __restrict__ Wlin, const float* __restrict__ blin,
                        float* __restrict__ out) {
    int idx = blockIdx.x * blockDim.x + threadIdx.x;
    if (idx >= N_GRAPHS * 2) return;
    int g = idx >> 1;
    int t = idx & 1;
    float inv = 1.0f / fmaxf(gcnt[g], 1.0f);
    float s = blin[t];
#pragma unroll
    for (int ff = 0; ff < H2; ++ff)
        s += gsum[g * H2 + ff] * inv * Wlin[ff * 2 + t];
    out[idx] = s;
}

static inline int cdiv(long long a, int b) { return (int)((a + b - 1) / b); }

extern "C" void kernel_launch(void* const* d_in, const int* in_sizes, int n_in,
                              void* d_out, int out_size, void* d_ws, size_t ws_size,
                              hipStream_t stream) {
    const float* x    = (const float*)d_in[0];
    const int*   ei   = (const int*)d_in[1];
    const int*   batch= (const int*)d_in[2];
    const float* W1   = (const float*)d_in[3];
    const float* b1   = (const float*)d_in[4];
    const float* W2   = (const float*)d_in[5];
    const float* b2   = (const float*)d_in[6];
    const float* Wlin = (const float*)d_in[7];
    const float* blin = (const float*)d_in[8];
    float* out = (float*)d_out;

    const int* src = ei;
    const int* dst = ei + N_EDGES;

    // ---- workspace layout ----
    f16*   t2   = (f16*)d_ws;                           // 32*(N+1) fp16
    f16*   sx   = t2 + 32LL * (N_NODES + 1);            // 8*(N+1) fp16
    float* dis  = (float*)(sx + 8LL * (N_NODES + 1));   // N f32
    float* gsum = dis + N_NODES;                        // 32G
    float* gcnt = gsum + (long long)N_GRAPHS * H2;      // G
    size_t ioff = ((size_t)(gcnt + N_GRAPHS) + 15) & ~(size_t)15;
    int*  bcur2   = (int*)ioff;                         // NBIN (+pad)
    int*  obeg    = bcur2 + NBIN + 16;                  // N
    int*  oend    = obeg + N_NODES;                     // N
    unsigned* benc2 = (unsigned*)(oend + N_NODES);      // NBIN*CAP2
    int*  csr      = (int*)(benc2 + (long long)NBIN * CAP2);  // NBIN*CAP2R

    const int B = 256;

    k_init<<<cdiv(N_GRAPHS * H2 + N_GRAPHS, B), B, 0, stream>>>(
        gsum, bcur2, t2 + 32LL * N_NODES, sx + 8LL * N_NODES);

    k_bin400<<<NSEGB, B, 0, stream>>>(src, dst, bcur2, benc2);
    k_sort<<<NBIN, B, 0, stream>>>(benc2, bcur2, x, csr, obeg, oend, dis, sx);

    k_l1<<<cdiv(N_NODES, 64), B, 0, stream>>>((const unsigned*)sx, obeg, oend, csr,
                                              W1, b1, W2, dis, t2);
    k_gather2<<<cdiv((long long)N_NODES * 16, B), B, 0, stream>>>(
        (const unsigned*)t2, obeg, oend, csr, dis, b2, batch, gsum, gcnt);
    k_final<<<cdiv(N_GRAPHS * 2, B), B, 0, stream>>>(gsum, gcnt, Wlin, blin, out);
}